// Round 10
// baseline (616.294 us; speedup 1.0000x reference)
//
#include <hip/hip_runtime.h>
#include <hip/hip_bf16.h>

// GraphSAGE(max) x3 + two heads on MI355X.
// R22: fused dual-head GEMM occupancy fix. R21 counters: heads 57.9us at
//      16% occupancy / 16% MfmaUtil / 6% HBM -- latency-bound, 1 block/CU.
//      Root cause: 80KB LDS (no headroom at 160KB) + launch_bounds(512,2)
//      unit bug (arg2 = waves/EU; "2" = 8 waves/CU = 1 block). Fix: K-step
//      32 -> 40KB LDS, launch_bounds(512,4) -> 2 blocks/CU co-resident.
//      Keeps A-dedup (FETCH 27.8MB confirmed the fusion's traffic win).
// R19 XCD-affinity scatter WON (354.1us best) -- kept.
// Walls (structural): agg 139us (fabric random-gather, 4 probes null),
//      prep ~50us (XCD-local atomics).
// edge_index arrives as int32 [2,E]: src = ei[e], dst = ei[NE + e].

#define NN 50000
#define NE 800000
#define HD 256

using bf16 = __hip_bfloat16;
typedef float f32x4 __attribute__((ext_vector_type(4)));
typedef short bf16x8 __attribute__((ext_vector_type(8)));

__device__ __forceinline__ void async16(const void* g, void* l) {
    __builtin_amdgcn_global_load_lds(
        (const __attribute__((address_space(1))) unsigned int*)g,
        (__attribute__((address_space(3))) unsigned int*)l, 16, 0, 0);
}

__device__ __forceinline__ unsigned short f2b(float f) {
    bf16 b = __float2bfloat16(f);
    return __builtin_bit_cast(unsigned short, b);
}

// ---------------- zero counters (must precede merged prep) ----------------
__global__ void k_zero(int* __restrict__ cnt) {
    int i = blockIdx.x * 256 + threadIdx.x;
    if (i < 2 * NN) cnt[i] = 0;
}

// ------- merged prep: scatter | cvt_x | pack weights (concurrent) ---------
__device__ __forceinline__ void pack1(const float* __restrict__ W,
                                      bf16* __restrict__ bt, int idx, int Ktot,
                                      int kofs) {
    int k = idx >> 8, n = idx & 255;
    bt[(size_t)n * Ktot + kofs + k] = __float2bfloat16(W[idx]);
}

#define SC_B 3200         // 8 node-groups x 400 edge-slices
#define EPS 2000          // edges per slice (400*2000 = NE)
#define GRP 6250          // nodes per group (NN/8)
#define PREP_CVT_B 6250   // NN*128/4/256
#define PREP_PACK_B 1792  // 458752/256
#define PREP_B (SC_B + PREP_CVT_B + PREP_PACK_B)

__global__ void k_prep(const int* __restrict__ ei, int* __restrict__ cnt,
                       unsigned short* __restrict__ srcp,
                       const float* __restrict__ x, bf16* __restrict__ xb,
                       const float* __restrict__ Wl1,
                       const float* __restrict__ Wr1,
                       const float* __restrict__ Wl2,
                       const float* __restrict__ Wr2,
                       const float* __restrict__ Wla,
                       const float* __restrict__ Wra,
                       const float* __restrict__ Wlm,
                       const float* __restrict__ Wrm, bf16* __restrict__ Bt1,
                       bf16* __restrict__ Bt2, bf16* __restrict__ Bta,
                       bf16* __restrict__ Btm) {
    int b = blockIdx.x;
    if (b < SC_B) {
        // XCD-affinity scatter: block handles only nodes in [glo, ghi),
        // scans edge slice s. Under round-robin dispatch all blocks with the
        // same (b&7) run on one XCD -> cnt/srcp lines stay XCD-local.
        const int g = b & 7;
        const int s = b >> 3;
        const int base = s * EPS;
        const int glo = g * GRP, ghi = glo + GRP;
#pragma unroll
        for (int i = 0; i < 8; ++i) {
            int e = base + i * 256 + threadIdx.x;
            if (e < base + EPS) {
                int d = ei[NE + e];
                if (d >= glo && d < ghi) {
                    int sub = e & 1;
                    int slot = atomicAdd(&cnt[sub * NN + d], 1);
                    if (slot < 32)
                        srcp[(d << 6) + (sub << 5) + slot] =
                            (unsigned short)ei[e];
                }
            }
        }
    } else if (b < SC_B + PREP_CVT_B) {
        int i = (b - SC_B) * 256 + threadIdx.x;  // < 1.6M exactly
        float4 v = ((const float4*)x)[i];
        ushort4 o;
        o.x = f2b(v.x); o.y = f2b(v.y); o.z = f2b(v.z); o.w = f2b(v.w);
        ((ushort4*)xb)[i] = o;
    } else {
        int idx = (b - SC_B - PREP_CVT_B) * 256 + threadIdx.x;  // < 458752
        if (idx < 32768) pack1(Wl1, Bt1, idx, 256, 0);
        else if (idx < 65536) pack1(Wr1, Bt1, idx - 32768, 256, 128);
        else if (idx < 131072) pack1(Wl2, Bt2, idx - 65536, 512, 0);
        else if (idx < 196608) pack1(Wr2, Bt2, idx - 131072, 512, 256);
        else if (idx < 262144) pack1(Wla, Bta, idx - 196608, 512, 0);
        else if (idx < 327680) pack1(Wra, Bta, idx - 262144, 512, 256);
        else if (idx < 393216) pack1(Wlm, Btm, idx - 327680, 512, 0);
        else pack1(Wrm, Btm, idx - 393216, 512, 256);
    }
}

// ---------------- segment-max aggregation (wide bucket gather) -------------
// One wave per node, two 32-slot sub-bucket segments. Rows packed
// multiple-per-wave-instruction:
//   EPL=4 (F=256): 2 rows/instr (lane half), merge shfl_xor(32).
//   EPL=2 (F=128): 4 rows/instr (lane quarter), merge 32 then 16.
// Clamped duplicate tail reads are idempotent under max.

__device__ __forceinline__ void amax8(float (&m)[8], uint4 v) {
    m[0] = fmaxf(m[0], __uint_as_float(v.x << 16));
    m[1] = fmaxf(m[1], __uint_as_float(v.x & 0xffff0000u));
    m[2] = fmaxf(m[2], __uint_as_float(v.y << 16));
    m[3] = fmaxf(m[3], __uint_as_float(v.y & 0xffff0000u));
    m[4] = fmaxf(m[4], __uint_as_float(v.z << 16));
    m[5] = fmaxf(m[5], __uint_as_float(v.z & 0xffff0000u));
    m[6] = fmaxf(m[6], __uint_as_float(v.w << 16));
    m[7] = fmaxf(m[7], __uint_as_float(v.w & 0xffff0000u));
}

__device__ __forceinline__ uint4 pack8(const float (&m)[8]) {
    uint4 r;
    r.x = (__float_as_uint(m[0]) >> 16) | (__float_as_uint(m[1]) & 0xffff0000u);
    r.y = (__float_as_uint(m[2]) >> 16) | (__float_as_uint(m[3]) & 0xffff0000u);
    r.z = (__float_as_uint(m[4]) >> 16) | (__float_as_uint(m[5]) & 0xffff0000u);
    r.w = (__float_as_uint(m[6]) >> 16) | (__float_as_uint(m[7]) & 0xffff0000u);
    return r;
}

template <int EPL>  // 2 (F=128) or 4 (F=256)
__global__ __launch_bounds__(256) void k_agg(
    const bf16* __restrict__ feat, bf16* __restrict__ agg,
    const int* __restrict__ cnt, const unsigned short* __restrict__ srcp) {
    int node = blockIdx.x * 4 + (threadIdx.x >> 6);
    if (node >= NN) return;
    int lane = threadIdx.x & 63;
    int c0r = cnt[node], c1r = cnt[NN + node];
    const uint4* __restrict__ f4 = (const uint4*)feat;
    float m[8];
#pragma unroll
    for (int i = 0; i < 8; ++i) m[i] = __int_as_float(0xff800000);  // -inf

    for (int seg = 0; seg < 2; ++seg) {
        const int n = min(seg ? c1r : c0r, 32);
        const unsigned short* __restrict__ lst =
            srcp + (node << 6) + (seg << 5);
        if (EPL == 4) {
            // F=256: row = 32 uint4. lanes 0-31 -> even slot, 32-63 -> odd.
            const int half = lane >> 5, sub = lane & 31;
            int e = 0;
            for (; e + 16 <= n; e += 16) {
                int s[8];
#pragma unroll
                for (int j = 0; j < 8; ++j) s[j] = lst[e + 2 * j + half];
                uint4 v[8];
#pragma unroll
                for (int j = 0; j < 8; ++j) v[j] = f4[(size_t)s[j] * 32 + sub];
#pragma unroll
                for (int j = 0; j < 8; ++j) amax8(m, v[j]);
            }
            int rem = n - e;  // 0..15
            if (rem > 8) {
                int s[8];
#pragma unroll
                for (int j = 0; j < 8; ++j) {
                    int ix = e + 2 * j + half;
                    s[j] = lst[ix < n ? ix : n - 1];
                }
                uint4 v[8];
#pragma unroll
                for (int j = 0; j < 8; ++j) v[j] = f4[(size_t)s[j] * 32 + sub];
#pragma unroll
                for (int j = 0; j < 8; ++j) amax8(m, v[j]);
            } else if (rem > 0) {
                int s[4];
#pragma unroll
                for (int j = 0; j < 4; ++j) {
                    int ix = e + 2 * j + half;
                    s[j] = lst[ix < n ? ix : n - 1];
                }
                uint4 v[4];
#pragma unroll
                for (int j = 0; j < 4; ++j) v[j] = f4[(size_t)s[j] * 32 + sub];
#pragma unroll
                for (int j = 0; j < 4; ++j) amax8(m, v[j]);
            }
        } else {
            // F=128: row = 16 uint4. lane quarter q picks row slot.
            const int q = lane >> 4, sub = lane & 15;
            int e = 0;
            for (; e + 32 <= n; e += 32) {
                int s[8];
#pragma unroll
                for (int j = 0; j < 8; ++j) s[j] = lst[e + 4 * j + q];
                uint4 v[8];
#pragma unroll
                for (int j = 0; j < 8; ++j) v[j] = f4[(size_t)s[j] * 16 + sub];
#pragma unroll
                for (int j = 0; j < 8; ++j) amax8(m, v[j]);
            }
            int rem = n - e;  // 0..31
            if (rem > 16) {
                int s[8];
#pragma unroll
                for (int j = 0; j < 8; ++j) {
                    int ix = e + 4 * j + q;
                    s[j] = lst[ix < n ? ix : n - 1];
                }
                uint4 v[8];
#pragma unroll
                for (int j = 0; j < 8; ++j) v[j] = f4[(size_t)s[j] * 16 + sub];
#pragma unroll
                for (int j = 0; j < 8; ++j) amax8(m, v[j]);
            } else if (rem > 8) {
                int s[4];
#pragma unroll
                for (int j = 0; j < 4; ++j) {
                    int ix = e + 4 * j + q;
                    s[j] = lst[ix < n ? ix : n - 1];
                }
                uint4 v[4];
#pragma unroll
                for (int j = 0; j < 4; ++j) v[j] = f4[(size_t)s[j] * 16 + sub];
#pragma unroll
                for (int j = 0; j < 4; ++j) amax8(m, v[j]);
            } else if (rem > 4) {
                int s[2];
#pragma unroll
                for (int j = 0; j < 2; ++j) {
                    int ix = e + 4 * j + q;
                    s[j] = lst[ix < n ? ix : n - 1];
                }
                uint4 v[2];
#pragma unroll
                for (int j = 0; j < 2; ++j) v[j] = f4[(size_t)s[j] * 16 + sub];
#pragma unroll
                for (int j = 0; j < 2; ++j) amax8(m, v[j]);
            } else if (rem > 0) {
                int ix = e + q;
                int s = lst[ix < n ? ix : n - 1];
                uint4 v = f4[(size_t)s * 16 + sub];
                amax8(m, v);
            }
        }
    }

    bool nonempty = (c0r + c1r) > 0;
    if (EPL == 4) {
#pragma unroll
        for (int i = 0; i < 8; ++i)
            m[i] = fmaxf(m[i], __shfl_xor(m[i], 32, 64));
        uint4 r = make_uint4(0, 0, 0, 0);
        if (nonempty) r = pack8(m);
        if (lane < 32) ((uint4*)agg)[(size_t)node * 32 + (lane & 31)] = r;
    } else {
#pragma unroll
        for (int i = 0; i < 8; ++i)
            m[i] = fmaxf(m[i], __shfl_xor(m[i], 32, 64));
#pragma unroll
        for (int i = 0; i < 8; ++i)
            m[i] = fmaxf(m[i], __shfl_xor(m[i], 16, 64));
        uint4 r = make_uint4(0, 0, 0, 0);
        if (nonempty) r = pack8(m);
        if (lane < 16) ((uint4*)agg)[(size_t)node * 16 + (lane & 15)] = r;
    }
}

// ------- MFMA GEMM core (128 rows x 256 cols): acc = [A0|A1] @ Bt^T -------
// Wave w: rows [(w>>1)*64, +64), cols [(w&1)*128, +128). acc[4][8].
__device__ __forceinline__ void gemm_core256(const bf16* __restrict__ A0,
                                             const bf16* __restrict__ A1, int F,
                                             int Ktot,
                                             const bf16* __restrict__ Bt,
                                             int bm0, int t, short* As,
                                             short* Bs, f32x4 (&acc)[4][8]) {
    const int wave = t >> 6;
    const int lane = t & 63;
    const int q = lane >> 4;
    const int c = lane & 15;
    const int wr = (wave >> 1) * 64;
    const int wcl = (wave & 1) * 128;

    for (int k0 = 0; k0 < Ktot; k0 += 64) {
        const bf16* Asrc = (k0 < F) ? A0 : A1;
        const int kk = (k0 < F) ? k0 : k0 - F;
        __syncthreads();
        // stage A tile [128 rows][64 k]: XOR-swizzled k-chunks (swizzle applied
        // to global addr so global_load_lds's lane-linear LDS layout holds)
#pragma unroll
        for (int it = 0; it < 4; ++it) {
            int chunk = it * 256 + t;
            int row = chunk >> 3, kc = chunk & 7;
            int kcg = kc ^ (row & 7);
            int grow = bm0 + row;
            if (grow > NN - 1) grow = NN - 1;
            async16(Asrc + (size_t)grow * F + kk + kcg * 8, &As[chunk * 8]);
        }
        // stage B tile [256 n][64 k]
#pragma unroll
        for (int it = 0; it < 8; ++it) {
            int chunk = it * 256 + t;
            int row = chunk >> 3, kc = chunk & 7;
            int kcg = kc ^ (row & 7);
            async16(Bt + (size_t)row * Ktot + k0 + kcg * 8, &Bs[chunk * 8]);
        }
        __syncthreads();
#pragma unroll
        for (int ks = 0; ks < 2; ++ks) {
            bf16x8 af[4], bfr[8];
            int ch = (ks * 4 + q) ^ (c & 7);
#pragma unroll
            for (int i = 0; i < 4; ++i)
                af[i] = *(const bf16x8*)&As[(wr + i * 16 + c) * 64 + ch * 8];
#pragma unroll
            for (int j = 0; j < 8; ++j)
                bfr[j] = *(const bf16x8*)&Bs[(wcl + j * 16 + c) * 64 + ch * 8];
#pragma unroll
            for (int i = 0; i < 4; ++i)
#pragma unroll
                for (int j = 0; j < 8; ++j)
                    acc[i][j] = __builtin_amdgcn_mfma_f32_16x16x32_bf16(
                        af[i], bfr[j], acc[i][j], 0, 0, 0);
        }
    }
}

// hidden-layer GEMM: Hout[row,col] = bf16(relu(acc + bias[col]))
__global__ __launch_bounds__(256, 2) void k_gemm_h(
    const bf16* __restrict__ A0, const bf16* __restrict__ A1, int F, int Ktot,
    const bf16* __restrict__ Bt, const float* __restrict__ bias,
    bf16* __restrict__ Hout) {
    __shared__ __attribute__((aligned(16))) short As[128 * 64];
    __shared__ __attribute__((aligned(16))) short Bs[256 * 64];
    const int t = threadIdx.x;
    const int bm0 = blockIdx.x * 128;
    const int wave = t >> 6;
    const int lane = t & 63;
    const int q = lane >> 4;
    const int c = lane & 15;
    const int wr = (wave >> 1) * 64;
    const int wcl = (wave & 1) * 128;

    f32x4 acc[4][8];
#pragma unroll
    for (int i = 0; i < 4; ++i)
#pragma unroll
        for (int j = 0; j < 8; ++j) acc[i][j] = (f32x4){0.f, 0.f, 0.f, 0.f};
    gemm_core256(A0, A1, F, Ktot, Bt, bm0, t, As, Bs, acc);

    float bcol[8];
#pragma unroll
    for (int j = 0; j < 8; ++j) bcol[j] = bias[wcl + j * 16 + c];
#pragma unroll
    for (int i = 0; i < 4; ++i)
#pragma unroll
        for (int r = 0; r < 4; ++r) {
            int row = bm0 + wr + i * 16 + q * 4 + r;  // C/D: row=quad*4+reg
            if (row < NN) {
#pragma unroll
                for (int j = 0; j < 8; ++j) {
                    int col = wcl + j * 16 + c;  // C/D: col=lane&15
                    float v = fmaxf(acc[i][j][r] + bcol[j], 0.f);
                    Hout[(size_t)row * HD + col] = __float2bfloat16(v);
                }
            }
        }
}

// fused dual-head GEMM (512 threads, 8 waves, K-step 32, 40KB LDS):
// wave w: rows [(w>>2)*64, +64), col-group cg=w&3 (128 cols each);
// cg 0-1 -> rtang (Bta/bla/Wa/ba), cg 2-3 -> movedis (Btm/blm/Wm/bm).
// One A-stage per K-step serves all 8 waves; Bs holds both B-tiles.
// launch_bounds(512,4): 4 waves/EU = 16 waves/CU = 2 blocks co-resident.
// out[z*NN+row] = hb + sum_col relu(acc + bias[col]) * Wh[col]
__global__ __launch_bounds__(512, 4) void k_gemm_heads(
    const bf16* __restrict__ A0, const bf16* __restrict__ A1,
    const bf16* __restrict__ Bta, const float* __restrict__ bla,
    const float* __restrict__ Wa, const float* __restrict__ ba,
    const bf16* __restrict__ Btm, const float* __restrict__ blm,
    const float* __restrict__ Wm, const float* __restrict__ bm,
    float* __restrict__ out) {
    __shared__ __attribute__((aligned(16))) short As[128 * 32];  // 8 KB
    __shared__ __attribute__((aligned(16))) short Bs[512 * 32];  // 32 KB
    const int t = threadIdx.x;  // 0..511
    const int bm0 = blockIdx.x * 128;
    const int wave = t >> 6;   // 0..7
    const int lane = t & 63;
    const int q = lane >> 4;
    const int c = lane & 15;
    const int wr = (wave >> 2) * 64;  // row group 0/1
    const int cg = wave & 3;          // col group 0..3
    const int z = cg >> 1;            // head: 0=rtang, 1=movedis
    const int wcl = cg * 128;         // col base in Bs (0..511)
    const int Ktot = 512, F = 256;

    f32x4 acc[4][8];
#pragma unroll
    for (int i = 0; i < 4; ++i)
#pragma unroll
        for (int j = 0; j < 8; ++j) acc[i][j] = (f32x4){0.f, 0.f, 0.f, 0.f};

    for (int k0 = 0; k0 < Ktot; k0 += 32) {
        const bf16* Asrc = (k0 < F) ? A0 : A1;
        const int kk = (k0 < F) ? k0 : k0 - F;
        __syncthreads();
        // stage A tile [128 rows][32 k]: 512 chunks / 512 threads, 4-chunk
        // rows, XOR-swizzle kc ^ (row&3) applied to global k-offset
        {
            int row = t >> 2, kc = t & 3;
            int kcg = kc ^ (row & 3);
            int grow = bm0 + row;
            if (grow > NN - 1) grow = NN - 1;
            async16(Asrc + (size_t)grow * F + kk + kcg * 8, &As[t * 8]);
        }
        // stage B tile [512 n][32 k]: rows 0-255 Bta, 256-511 Btm
#pragma unroll
        for (int it = 0; it < 4; ++it) {
            int chunk = it * 512 + t;
            int row = chunk >> 2, kc = chunk & 3;
            int kcg = kc ^ (row & 3);
            const bf16* B = (row < 256) ? Bta : Btm;
            int brow = row & 255;
            async16(B + (size_t)brow * Ktot + k0 + kcg * 8, &Bs[chunk * 8]);
        }
        __syncthreads();
        {
            bf16x8 af[4], bfr[8];
            int ch = q ^ (c & 3);  // logical chunk q, rows ≡ c (mod 4)
#pragma unroll
            for (int i = 0; i < 4; ++i)
                af[i] = *(const bf16x8*)&As[(wr + i * 16 + c) * 32 + ch * 8];
#pragma unroll
            for (int j = 0; j < 8; ++j)
                bfr[j] = *(const bf16x8*)&Bs[(wcl + j * 16 + c) * 32 + ch * 8];
#pragma unroll
            for (int i = 0; i < 4; ++i)
#pragma unroll
                for (int j = 0; j < 8; ++j)
                    acc[i][j] = __builtin_amdgcn_mfma_f32_16x16x32_bf16(
                        af[i], bfr[j], acc[i][j], 0, 0, 0);
        }
    }

    const float* bias = z ? blm : bla;
    const float* Wh = z ? Wm : Wa;
    const float hb = z ? bm[0] : ba[0];
    float* outp = out + (size_t)z * NN;
    const int colbase = (cg & 1) * 128;  // within-head col base
    float bcol[8], wcol[8];
#pragma unroll
    for (int j = 0; j < 8; ++j) {
        int col = colbase + j * 16 + c;
        bcol[j] = bias[col];
        wcol[j] = Wh[col];
    }
    // per-(i,r) partial dot over this wave's 128 cols
    float pr[4][4];
#pragma unroll
    for (int i = 0; i < 4; ++i)
#pragma unroll
        for (int r = 0; r < 4; ++r) {
            float p = 0.f;
#pragma unroll
            for (int j = 0; j < 8; ++j)
                p += fmaxf(acc[i][j][r] + bcol[j], 0.f) * wcol[j];
            p += __shfl_xor(p, 1, 64);
            p += __shfl_xor(p, 2, 64);
            p += __shfl_xor(p, 4, 64);
            p += __shfl_xor(p, 8, 64);
            pr[i][r] = p;  // valid at c==0 lanes
        }
    // wave pairs (w, w^1) share rows+head, cover within-head cols 0-127/128-255
    __syncthreads();
    float* red = (float*)As;      // 4 regions x 64 floats (1KB < 8KB)
    const int region = wave >> 1; // pair id 0..3
    if ((wave & 1) && c == 0) {
#pragma unroll
        for (int i = 0; i < 4; ++i)
#pragma unroll
            for (int r = 0; r < 4; ++r)
                red[region * 64 + i * 16 + q * 4 + r] = pr[i][r];
    }
    __syncthreads();
    if (!(wave & 1) && c == 0) {
#pragma unroll
        for (int i = 0; i < 4; ++i)
#pragma unroll
            for (int r = 0; r < 4; ++r) {
                int lr = i * 16 + q * 4 + r;
                int row = bm0 + wr + lr;
                if (row < NN)
                    outp[row] = pr[i][r] + red[region * 64 + lr] + hb;
            }
    }
}

extern "C" void kernel_launch(void* const* d_in, const int* in_sizes, int n_in,
                              void* d_out, int out_size, void* d_ws,
                              size_t ws_size, hipStream_t stream) {
    const float* x = (const float*)d_in[0];
    const int* ei = (const int*)d_in[1];  // int32 [2,E]
    const float* Wl1 = (const float*)d_in[2];
    const float* bl1 = (const float*)d_in[3];
    const float* Wr1 = (const float*)d_in[4];
    const float* Wl2 = (const float*)d_in[5];
    const float* bl2 = (const float*)d_in[6];
    const float* Wr2 = (const float*)d_in[7];
    const float* Wla = (const float*)d_in[8];
    const float* bla = (const float*)d_in[9];
    const float* Wra = (const float*)d_in[10];
    const float* Wa = (const float*)d_in[11];
    const float* ba = (const float*)d_in[12];
    const float* Wlm = (const float*)d_in[13];
    const float* blm = (const float*)d_in[14];
    const float* Wrm = (const float*)d_in[15];
    const float* Wm = (const float*)d_in[16];
    const float* bm = (const float*)d_in[17];
    float* out = (float*)d_out;

    char* ws = (char*)d_ws;
    size_t off = 0;
    auto alloc = [&](size_t b) {
        void* p = ws + off;
        off = (off + b + 255) & ~(size_t)255;
        return p;
    };
    unsigned short* srcp = (unsigned short*)alloc((size_t)NN * 64 * 2);
    int* cnt = (int*)alloc((size_t)2 * NN * 4);
    bf16* xb = (bf16*)alloc((size_t)NN * 128 * 2);
    bf16* h1 = (bf16*)alloc((size_t)NN * 256 * 2);
    bf16* h2 = (bf16*)alloc((size_t)NN * 256 * 2);
    bf16* agg = (bf16*)alloc((size_t)NN * 256 * 2);
    bf16* Bt1 = (bf16*)alloc((size_t)256 * 256 * 2);
    bf16* Bt2 = (bf16*)alloc((size_t)256 * 512 * 2);
    bf16* Bta = (bf16*)alloc((size_t)256 * 512 * 2);
    bf16* Btm = (bf16*)alloc((size_t)256 * 512 * 2);
    (void)ws_size; (void)in_sizes; (void)n_in; (void)out_size;

    // zero counters, then merged {scatter | cvt_x | pack} (concurrent blocks)
    k_zero<<<(2 * NN + 255) / 256, 256, 0, stream>>>(cnt);
    k_prep<<<PREP_B, 256, 0, stream>>>(ei, cnt, srcp, x, xb, Wl1, Wr1, Wl2,
                                       Wr2, Wla, Wra, Wlm, Wrm, Bt1, Bt2, Bta,
                                       Btm);

    const int GB = (NN + 127) / 128;  // 391
    const int NG4 = (NN + 3) / 4;     // 12500
    // layer 1
    k_agg<2><<<NG4, 256, 0, stream>>>(xb, agg, cnt, srcp);
    k_gemm_h<<<GB, 256, 0, stream>>>(agg, xb, 128, 256, Bt1, bl1, h1);
    // layer 2
    k_agg<4><<<NG4, 256, 0, stream>>>(h1, agg, cnt, srcp);
    k_gemm_h<<<GB, 256, 0, stream>>>(agg, h1, 256, 512, Bt2, bl2, h2);
    // layer 3 (shared aggregation) + fused dual-head GEMM
    k_agg<4><<<NG4, 256, 0, stream>>>(h2, agg, cnt, srcp);
    k_gemm_heads<<<GB, 512, 0, stream>>>(agg, h2, Bta, bla, Wa, ba, Btm, blm,
                                         Wm, bm, out);
}

// Round 11
// 350.302 us; speedup vs baseline: 1.7593x; 1.7593x over previous
//
#include <hip/hip_runtime.h>
#include <hip/hip_bf16.h>

// GraphSAGE(max) x3 + two heads on MI355X.
// R23: exact revert to R19 (measured best 354.1us). R20-R22 fused-head arc
//      net-negative: R21 = 1 block/CU latency-bound (80KB LDS + wave-bound
//      unit bug); R22 = VGPR spill catastrophe (launch_bounds(512,4) capped
//      alloc at 64 < acc's 128 -> 1.3GB scratch traffic, 327us) + 4-way
//      swizzle bank conflicts (2.4M). Lessons: never bound VGPRs below the
//      accumulator footprint; K-step 64 required for full c&7 XOR spread.
// R19 XCD-affinity scatter WON -- kept (prep out of top-5).
// Walls (structural): agg 139us (fabric random-gather, R14/R16 null),
//      prep ~50us (atomic transaction wall, R15/R17 null, R19 captured).
// edge_index arrives as int32 [2,E]: src = ei[e], dst = ei[NE + e].

#define NN 50000
#define NE 800000
#define HD 256

using bf16 = __hip_bfloat16;
typedef float f32x4 __attribute__((ext_vector_type(4)));
typedef short bf16x8 __attribute__((ext_vector_type(8)));

__device__ __forceinline__ void async16(const void* g, void* l) {
    __builtin_amdgcn_global_load_lds(
        (const __attribute__((address_space(1))) unsigned int*)g,
        (__attribute__((address_space(3))) unsigned int*)l, 16, 0, 0);
}

__device__ __forceinline__ unsigned short f2b(float f) {
    bf16 b = __float2bfloat16(f);
    return __builtin_bit_cast(unsigned short, b);
}

// ---------------- zero counters (must precede merged prep) ----------------
__global__ void k_zero(int* __restrict__ cnt) {
    int i = blockIdx.x * 256 + threadIdx.x;
    if (i < 2 * NN) cnt[i] = 0;
}

// ------- merged prep: scatter | cvt_x | pack weights (concurrent) ---------
__device__ __forceinline__ void pack1(const float* __restrict__ W,
                                      bf16* __restrict__ bt, int idx, int Ktot,
                                      int kofs) {
    int k = idx >> 8, n = idx & 255;
    bt[(size_t)n * Ktot + kofs + k] = __float2bfloat16(W[idx]);
}

#define SC_B 3200         // 8 node-groups x 400 edge-slices
#define EPS 2000          // edges per slice (400*2000 = NE)
#define GRP 6250          // nodes per group (NN/8)
#define PREP_CVT_B 6250   // NN*128/4/256
#define PREP_PACK_B 1792  // 458752/256
#define PREP_B (SC_B + PREP_CVT_B + PREP_PACK_B)

__global__ void k_prep(const int* __restrict__ ei, int* __restrict__ cnt,
                       unsigned short* __restrict__ srcp,
                       const float* __restrict__ x, bf16* __restrict__ xb,
                       const float* __restrict__ Wl1,
                       const float* __restrict__ Wr1,
                       const float* __restrict__ Wl2,
                       const float* __restrict__ Wr2,
                       const float* __restrict__ Wla,
                       const float* __restrict__ Wra,
                       const float* __restrict__ Wlm,
                       const float* __restrict__ Wrm, bf16* __restrict__ Bt1,
                       bf16* __restrict__ Bt2, bf16* __restrict__ Bta,
                       bf16* __restrict__ Btm) {
    int b = blockIdx.x;
    if (b < SC_B) {
        // XCD-affinity scatter: block handles only nodes in [glo, ghi),
        // scans edge slice s. Under round-robin dispatch all blocks with the
        // same (b&7) run on one XCD -> cnt/srcp lines stay XCD-local.
        const int g = b & 7;
        const int s = b >> 3;
        const int base = s * EPS;
        const int glo = g * GRP, ghi = glo + GRP;
#pragma unroll
        for (int i = 0; i < 8; ++i) {
            int e = base + i * 256 + threadIdx.x;
            if (e < base + EPS) {
                int d = ei[NE + e];
                if (d >= glo && d < ghi) {
                    int sub = e & 1;
                    int slot = atomicAdd(&cnt[sub * NN + d], 1);
                    if (slot < 32)
                        srcp[(d << 6) + (sub << 5) + slot] =
                            (unsigned short)ei[e];
                }
            }
        }
    } else if (b < SC_B + PREP_CVT_B) {
        int i = (b - SC_B) * 256 + threadIdx.x;  // < 1.6M exactly
        float4 v = ((const float4*)x)[i];
        ushort4 o;
        o.x = f2b(v.x); o.y = f2b(v.y); o.z = f2b(v.z); o.w = f2b(v.w);
        ((ushort4*)xb)[i] = o;
    } else {
        int idx = (b - SC_B - PREP_CVT_B) * 256 + threadIdx.x;  // < 458752
        if (idx < 32768) pack1(Wl1, Bt1, idx, 256, 0);
        else if (idx < 65536) pack1(Wr1, Bt1, idx - 32768, 256, 128);
        else if (idx < 131072) pack1(Wl2, Bt2, idx - 65536, 512, 0);
        else if (idx < 196608) pack1(Wr2, Bt2, idx - 131072, 512, 256);
        else if (idx < 262144) pack1(Wla, Bta, idx - 196608, 512, 0);
        else if (idx < 327680) pack1(Wra, Bta, idx - 262144, 512, 256);
        else if (idx < 393216) pack1(Wlm, Btm, idx - 327680, 512, 0);
        else pack1(Wrm, Btm, idx - 393216, 512, 256);
    }
}

// ---------------- segment-max aggregation (wide bucket gather) -------------
// One wave per node, two 32-slot sub-bucket segments. Rows packed
// multiple-per-wave-instruction:
//   EPL=4 (F=256): 2 rows/instr (lane half), merge shfl_xor(32).
//   EPL=2 (F=128): 4 rows/instr (lane quarter), merge 32 then 16.
// Clamped duplicate tail reads are idempotent under max.

__device__ __forceinline__ void amax8(float (&m)[8], uint4 v) {
    m[0] = fmaxf(m[0], __uint_as_float(v.x << 16));
    m[1] = fmaxf(m[1], __uint_as_float(v.x & 0xffff0000u));
    m[2] = fmaxf(m[2], __uint_as_float(v.y << 16));
    m[3] = fmaxf(m[3], __uint_as_float(v.y & 0xffff0000u));
    m[4] = fmaxf(m[4], __uint_as_float(v.z << 16));
    m[5] = fmaxf(m[5], __uint_as_float(v.z & 0xffff0000u));
    m[6] = fmaxf(m[6], __uint_as_float(v.w << 16));
    m[7] = fmaxf(m[7], __uint_as_float(v.w & 0xffff0000u));
}

__device__ __forceinline__ uint4 pack8(const float (&m)[8]) {
    uint4 r;
    r.x = (__float_as_uint(m[0]) >> 16) | (__float_as_uint(m[1]) & 0xffff0000u);
    r.y = (__float_as_uint(m[2]) >> 16) | (__float_as_uint(m[3]) & 0xffff0000u);
    r.z = (__float_as_uint(m[4]) >> 16) | (__float_as_uint(m[5]) & 0xffff0000u);
    r.w = (__float_as_uint(m[6]) >> 16) | (__float_as_uint(m[7]) & 0xffff0000u);
    return r;
}

template <int EPL>  // 2 (F=128) or 4 (F=256)
__global__ __launch_bounds__(256) void k_agg(
    const bf16* __restrict__ feat, bf16* __restrict__ agg,
    const int* __restrict__ cnt, const unsigned short* __restrict__ srcp) {
    int node = blockIdx.x * 4 + (threadIdx.x >> 6);
    if (node >= NN) return;
    int lane = threadIdx.x & 63;
    int c0r = cnt[node], c1r = cnt[NN + node];
    const uint4* __restrict__ f4 = (const uint4*)feat;
    float m[8];
#pragma unroll
    for (int i = 0; i < 8; ++i) m[i] = __int_as_float(0xff800000);  // -inf

    for (int seg = 0; seg < 2; ++seg) {
        const int n = min(seg ? c1r : c0r, 32);
        const unsigned short* __restrict__ lst =
            srcp + (node << 6) + (seg << 5);
        if (EPL == 4) {
            // F=256: row = 32 uint4. lanes 0-31 -> even slot, 32-63 -> odd.
            const int half = lane >> 5, sub = lane & 31;
            int e = 0;
            for (; e + 16 <= n; e += 16) {
                int s[8];
#pragma unroll
                for (int j = 0; j < 8; ++j) s[j] = lst[e + 2 * j + half];
                uint4 v[8];
#pragma unroll
                for (int j = 0; j < 8; ++j) v[j] = f4[(size_t)s[j] * 32 + sub];
#pragma unroll
                for (int j = 0; j < 8; ++j) amax8(m, v[j]);
            }
            int rem = n - e;  // 0..15
            if (rem > 8) {
                int s[8];
#pragma unroll
                for (int j = 0; j < 8; ++j) {
                    int ix = e + 2 * j + half;
                    s[j] = lst[ix < n ? ix : n - 1];
                }
                uint4 v[8];
#pragma unroll
                for (int j = 0; j < 8; ++j) v[j] = f4[(size_t)s[j] * 32 + sub];
#pragma unroll
                for (int j = 0; j < 8; ++j) amax8(m, v[j]);
            } else if (rem > 0) {
                int s[4];
#pragma unroll
                for (int j = 0; j < 4; ++j) {
                    int ix = e + 2 * j + half;
                    s[j] = lst[ix < n ? ix : n - 1];
                }
                uint4 v[4];
#pragma unroll
                for (int j = 0; j < 4; ++j) v[j] = f4[(size_t)s[j] * 32 + sub];
#pragma unroll
                for (int j = 0; j < 4; ++j) amax8(m, v[j]);
            }
        } else {
            // F=128: row = 16 uint4. lane quarter q picks row slot.
            const int q = lane >> 4, sub = lane & 15;
            int e = 0;
            for (; e + 32 <= n; e += 32) {
                int s[8];
#pragma unroll
                for (int j = 0; j < 8; ++j) s[j] = lst[e + 4 * j + q];
                uint4 v[8];
#pragma unroll
                for (int j = 0; j < 8; ++j) v[j] = f4[(size_t)s[j] * 16 + sub];
#pragma unroll
                for (int j = 0; j < 8; ++j) amax8(m, v[j]);
            }
            int rem = n - e;  // 0..31
            if (rem > 16) {
                int s[8];
#pragma unroll
                for (int j = 0; j < 8; ++j) {
                    int ix = e + 4 * j + q;
                    s[j] = lst[ix < n ? ix : n - 1];
                }
                uint4 v[8];
#pragma unroll
                for (int j = 0; j < 8; ++j) v[j] = f4[(size_t)s[j] * 16 + sub];
#pragma unroll
                for (int j = 0; j < 8; ++j) amax8(m, v[j]);
            } else if (rem > 8) {
                int s[4];
#pragma unroll
                for (int j = 0; j < 4; ++j) {
                    int ix = e + 4 * j + q;
                    s[j] = lst[ix < n ? ix : n - 1];
                }
                uint4 v[4];
#pragma unroll
                for (int j = 0; j < 4; ++j) v[j] = f4[(size_t)s[j] * 16 + sub];
#pragma unroll
                for (int j = 0; j < 4; ++j) amax8(m, v[j]);
            } else if (rem > 4) {
                int s[2];
#pragma unroll
                for (int j = 0; j < 2; ++j) {
                    int ix = e + 4 * j + q;
                    s[j] = lst[ix < n ? ix : n - 1];
                }
                uint4 v[2];
#pragma unroll
                for (int j = 0; j < 2; ++j) v[j] = f4[(size_t)s[j] * 16 + sub];
#pragma unroll
                for (int j = 0; j < 2; ++j) amax8(m, v[j]);
            } else if (rem > 0) {
                int ix = e + q;
                int s = lst[ix < n ? ix : n - 1];
                uint4 v = f4[(size_t)s * 16 + sub];
                amax8(m, v);
            }
        }
    }

    bool nonempty = (c0r + c1r) > 0;
    if (EPL == 4) {
#pragma unroll
        for (int i = 0; i < 8; ++i)
            m[i] = fmaxf(m[i], __shfl_xor(m[i], 32, 64));
        uint4 r = make_uint4(0, 0, 0, 0);
        if (nonempty) r = pack8(m);
        if (lane < 32) ((uint4*)agg)[(size_t)node * 32 + (lane & 31)] = r;
    } else {
#pragma unroll
        for (int i = 0; i < 8; ++i)
            m[i] = fmaxf(m[i], __shfl_xor(m[i], 32, 64));
#pragma unroll
        for (int i = 0; i < 8; ++i)
            m[i] = fmaxf(m[i], __shfl_xor(m[i], 16, 64));
        uint4 r = make_uint4(0, 0, 0, 0);
        if (nonempty) r = pack8(m);
        if (lane < 16) ((uint4*)agg)[(size_t)node * 16 + (lane & 15)] = r;
    }
}

// ------- MFMA GEMM core (128 rows x 256 cols): acc = [A0|A1] @ Bt^T -------
// Wave w: rows [(w>>1)*64, +64), cols [(w&1)*128, +128). acc[4][8].
__device__ __forceinline__ void gemm_core256(const bf16* __restrict__ A0,
                                             const bf16* __restrict__ A1, int F,
                                             int Ktot,
                                             const bf16* __restrict__ Bt,
                                             int bm0, int t, short* As,
                                             short* Bs, f32x4 (&acc)[4][8]) {
    const int wave = t >> 6;
    const int lane = t & 63;
    const int q = lane >> 4;
    const int c = lane & 15;
    const int wr = (wave >> 1) * 64;
    const int wcl = (wave & 1) * 128;

    for (int k0 = 0; k0 < Ktot; k0 += 64) {
        const bf16* Asrc = (k0 < F) ? A0 : A1;
        const int kk = (k0 < F) ? k0 : k0 - F;
        __syncthreads();
        // stage A tile [128 rows][64 k]: XOR-swizzled k-chunks (swizzle applied
        // to global addr so global_load_lds's lane-linear LDS layout holds)
#pragma unroll
        for (int it = 0; it < 4; ++it) {
            int chunk = it * 256 + t;
            int row = chunk >> 3, kc = chunk & 7;
            int kcg = kc ^ (row & 7);
            int grow = bm0 + row;
            if (grow > NN - 1) grow = NN - 1;
            async16(Asrc + (size_t)grow * F + kk + kcg * 8, &As[chunk * 8]);
        }
        // stage B tile [256 n][64 k]
#pragma unroll
        for (int it = 0; it < 8; ++it) {
            int chunk = it * 256 + t;
            int row = chunk >> 3, kc = chunk & 7;
            int kcg = kc ^ (row & 7);
            async16(Bt + (size_t)row * Ktot + k0 + kcg * 8, &Bs[chunk * 8]);
        }
        __syncthreads();
#pragma unroll
        for (int ks = 0; ks < 2; ++ks) {
            bf16x8 af[4], bfr[8];
            int ch = (ks * 4 + q) ^ (c & 7);
#pragma unroll
            for (int i = 0; i < 4; ++i)
                af[i] = *(const bf16x8*)&As[(wr + i * 16 + c) * 64 + ch * 8];
#pragma unroll
            for (int j = 0; j < 8; ++j)
                bfr[j] = *(const bf16x8*)&Bs[(wcl + j * 16 + c) * 64 + ch * 8];
#pragma unroll
            for (int i = 0; i < 4; ++i)
#pragma unroll
                for (int j = 0; j < 8; ++j)
                    acc[i][j] = __builtin_amdgcn_mfma_f32_16x16x32_bf16(
                        af[i], bfr[j], acc[i][j], 0, 0, 0);
        }
    }
}

// hidden-layer GEMM: Hout[row,col] = bf16(relu(acc + bias[col]))
__global__ __launch_bounds__(256, 2) void k_gemm_h(
    const bf16* __restrict__ A0, const bf16* __restrict__ A1, int F, int Ktot,
    const bf16* __restrict__ Bt, const float* __restrict__ bias,
    bf16* __restrict__ Hout) {
    __shared__ __attribute__((aligned(16))) short As[128 * 64];
    __shared__ __attribute__((aligned(16))) short Bs[256 * 64];
    const int t = threadIdx.x;
    const int bm0 = blockIdx.x * 128;
    const int wave = t >> 6;
    const int lane = t & 63;
    const int q = lane >> 4;
    const int c = lane & 15;
    const int wr = (wave >> 1) * 64;
    const int wcl = (wave & 1) * 128;

    f32x4 acc[4][8];
#pragma unroll
    for (int i = 0; i < 4; ++i)
#pragma unroll
        for (int j = 0; j < 8; ++j) acc[i][j] = (f32x4){0.f, 0.f, 0.f, 0.f};
    gemm_core256(A0, A1, F, Ktot, Bt, bm0, t, As, Bs, acc);

    float bcol[8];
#pragma unroll
    for (int j = 0; j < 8; ++j) bcol[j] = bias[wcl + j * 16 + c];
#pragma unroll
    for (int i = 0; i < 4; ++i)
#pragma unroll
        for (int r = 0; r < 4; ++r) {
            int row = bm0 + wr + i * 16 + q * 4 + r;  // C/D: row=quad*4+reg
            if (row < NN) {
#pragma unroll
                for (int j = 0; j < 8; ++j) {
                    int col = wcl + j * 16 + c;  // C/D: col=lane&15
                    float v = fmaxf(acc[i][j][r] + bcol[j], 0.f);
                    Hout[(size_t)row * HD + col] = __float2bfloat16(v);
                }
            }
        }
}

// head GEMM (blockIdx.y: 0=rtang, 1=movedis):
// out[z*NN+row] = hb + sum_col relu(acc + bias[col]) * Wh[col]  (direct store)
__global__ __launch_bounds__(256, 2) void k_gemm_heads(
    const bf16* __restrict__ A0, const bf16* __restrict__ A1,
    const bf16* __restrict__ Bta, const float* __restrict__ bla,
    const float* __restrict__ Wa, const float* __restrict__ ba,
    const bf16* __restrict__ Btm, const float* __restrict__ blm,
    const float* __restrict__ Wm, const float* __restrict__ bm,
    float* __restrict__ out) {
    __shared__ __attribute__((aligned(16))) short As[128 * 64];
    __shared__ __attribute__((aligned(16))) short Bs[256 * 64];
    const int t = threadIdx.x;
    const int bm0 = blockIdx.x * 128;
    const int z = blockIdx.y;
    const bf16* Bt = z ? Btm : Bta;
    const float* bias = z ? blm : bla;
    const float* Wh = z ? Wm : Wa;
    const float hb = z ? bm[0] : ba[0];
    float* outp = out + (size_t)z * NN;
    const int wave = t >> 6;
    const int lane = t & 63;
    const int q = lane >> 4;
    const int c = lane & 15;
    const int wr = (wave >> 1) * 64;
    const int wcl = (wave & 1) * 128;

    f32x4 acc[4][8];
#pragma unroll
    for (int i = 0; i < 4; ++i)
#pragma unroll
        for (int j = 0; j < 8; ++j) acc[i][j] = (f32x4){0.f, 0.f, 0.f, 0.f};
    gemm_core256(A0, A1, 256, 512, Bt, bm0, t, As, Bs, acc);

    float bcol[8], wcol[8];
#pragma unroll
    for (int j = 0; j < 8; ++j) {
        int col = wcl + j * 16 + c;
        bcol[j] = bias[col];
        wcol[j] = Wh[col];
    }
    // per-(i,r) partial dot over this wave's 128 cols
    float pr[4][4];
#pragma unroll
    for (int i = 0; i < 4; ++i)
#pragma unroll
        for (int r = 0; r < 4; ++r) {
            float p = 0.f;
#pragma unroll
            for (int j = 0; j < 8; ++j)
                p += fmaxf(acc[i][j][r] + bcol[j], 0.f) * wcol[j];
            p += __shfl_xor(p, 1, 64);
            p += __shfl_xor(p, 2, 64);
            p += __shfl_xor(p, 4, 64);
            p += __shfl_xor(p, 8, 64);
            pr[i][r] = p;  // valid at c==0 lanes
        }
    // cross-wave pair (w, w^1) share rows, cover cols 0-127 / 128-255
    __syncthreads();
    float* red = (float*)As;
    if ((wave & 1) && c == 0) {
#pragma unroll
        for (int i = 0; i < 4; ++i)
#pragma unroll
            for (int r = 0; r < 4; ++r) red[wr + i * 16 + q * 4 + r] = pr[i][r];
    }
    __syncthreads();
    if (!(wave & 1) && c == 0) {
#pragma unroll
        for (int i = 0; i < 4; ++i)
#pragma unroll
            for (int r = 0; r < 4; ++r) {
                int lr = wr + i * 16 + q * 4 + r;
                int row = bm0 + lr;
                if (row < NN) outp[row] = pr[i][r] + red[lr] + hb;
            }
    }
}

extern "C" void kernel_launch(void* const* d_in, const int* in_sizes, int n_in,
                              void* d_out, int out_size, void* d_ws,
                              size_t ws_size, hipStream_t stream) {
    const float* x = (const float*)d_in[0];
    const int* ei = (const int*)d_in[1];  // int32 [2,E]
    const float* Wl1 = (const float*)d_in[2];
    const float* bl1 = (const float*)d_in[3];
    const float* Wr1 = (const float*)d_in[4];
    const float* Wl2 = (const float*)d_in[5];
    const float* bl2 = (const float*)d_in[6];
    const float* Wr2 = (const float*)d_in[7];
    const float* Wla = (const float*)d_in[8];
    const float* bla = (const float*)d_in[9];
    const float* Wra = (const float*)d_in[10];
    const float* Wa = (const float*)d_in[11];
    const float* ba = (const float*)d_in[12];
    const float* Wlm = (const float*)d_in[13];
    const float* blm = (const float*)d_in[14];
    const float* Wrm = (const float*)d_in[15];
    const float* Wm = (const float*)d_in[16];
    const float* bm = (const float*)d_in[17];
    float* out = (float*)d_out;

    char* ws = (char*)d_ws;
    size_t off = 0;
    auto alloc = [&](size_t b) {
        void* p = ws + off;
        off = (off + b + 255) & ~(size_t)255;
        return p;
    };
    unsigned short* srcp = (unsigned short*)alloc((size_t)NN * 64 * 2);
    int* cnt = (int*)alloc((size_t)2 * NN * 4);
    bf16* xb = (bf16*)alloc((size_t)NN * 128 * 2);
    bf16* h1 = (bf16*)alloc((size_t)NN * 256 * 2);
    bf16* h2 = (bf16*)alloc((size_t)NN * 256 * 2);
    bf16* agg = (bf16*)alloc((size_t)NN * 256 * 2);
    bf16* Bt1 = (bf16*)alloc((size_t)256 * 256 * 2);
    bf16* Bt2 = (bf16*)alloc((size_t)256 * 512 * 2);
    bf16* Bta = (bf16*)alloc((size_t)256 * 512 * 2);
    bf16* Btm = (bf16*)alloc((size_t)256 * 512 * 2);
    (void)ws_size; (void)in_sizes; (void)n_in; (void)out_size;

    // zero counters, then merged {scatter | cvt_x | pack} (concurrent blocks)
    k_zero<<<(2 * NN + 255) / 256, 256, 0, stream>>>(cnt);
    k_prep<<<PREP_B, 256, 0, stream>>>(ei, cnt, srcp, x, xb, Wl1, Wr1, Wl2,
                                       Wr2, Wla, Wra, Wlm, Wrm, Bt1, Bt2, Bta,
                                       Btm);

    const int GB = (NN + 127) / 128;  // 391
    const int NG4 = (NN + 3) / 4;     // 12500
    // layer 1
    k_agg<2><<<NG4, 256, 0, stream>>>(xb, agg, cnt, srcp);
    k_gemm_h<<<GB, 256, 0, stream>>>(agg, xb, 128, 256, Bt1, bl1, h1);
    // layer 2
    k_agg<4><<<NG4, 256, 0, stream>>>(h1, agg, cnt, srcp);
    k_gemm_h<<<GB, 256, 0, stream>>>(agg, h1, 256, 512, Bt2, bl2, h2);
    // layer 3 (shared aggregation) + both heads in one launch (y = head)
    k_agg<4><<<NG4, 256, 0, stream>>>(h2, agg, cnt, srcp);
    dim3 gh(GB, 2);
    k_gemm_heads<<<gh, 256, 0, stream>>>(agg, h2, Bta, bla, Wa, ba, Btm, blm,
                                         Wm, bm, out);
}